// Round 18
// baseline (178.085 us; speedup 1.0000x reference)
//
#include <hip/hip_runtime.h>

typedef _Float16 half_t;
typedef _Float16 half4 __attribute__((ext_vector_type(4)));
typedef _Float16 half8 __attribute__((ext_vector_type(8)));
typedef float f32x4 __attribute__((ext_vector_type(4)));

#define AS1 __attribute__((address_space(1)))
#define AS3 __attribute__((address_space(3)))

static constexpr int NBATCH = 65536;

__device__ __forceinline__ bool is_alpha(int c) {
  const unsigned long long AM0 =
      (1ull << 0) | (1ull << 11) | (1ull << 20) | (1ull << 31) | (1ull << 37) |
      (1ull << 48) | (1ull << 59);
  const unsigned long long AM1 = (1ull << 3) | (1ull << 14) | (1ull << 25);  // 67,78,89
  if (c >= 90) return false;
  return (((c < 64) ? (AM0 >> c) : (AM1 >> (c - 64))) & 1ull) != 0ull;
}

// BN+ReLU on a half8 fragment: packed fma + packed max (R14/R15 lesson).
__device__ __forceinline__ half8 bn8(half8 x, half8 sc, half8 sh, half8 lo) {
  return __builtin_elementwise_max(x * sc + sh, lo);
}

// ---------- merged prep: z cvt + 3 weight transposes + identity table tails ----------
__global__ __launch_bounds__(256) void k_prep(
    const float* __restrict__ z, half_t* __restrict__ zdst,
    const float* __restrict__ W1, half_t* __restrict__ W1t,
    const float* __restrict__ W2, half_t* __restrict__ W2t,
    const float* __restrict__ Wout, half_t* __restrict__ Wot,
    half_t* __restrict__ t2sc, half_t* __restrict__ t2sh, half_t* __restrict__ t2lo,
    half_t* __restrict__ t3sc, half_t* __restrict__ t3sh, half_t* __restrict__ t3lo) {
  const int b = blockIdx.x;
  const int tid = threadIdx.x;
  if (b < 4096) {
    size_t i = (size_t)b * 256 + tid;
    int row = (int)(i >> 4), c8 = (int)(i & 15) << 3;
    const float* s = z + (size_t)row * 128 + c8;
    float4 v0 = *(const float4*)s;
    float4 v1 = *(const float4*)(s + 4);
    half8 h;
    h[0]=(half_t)v0.x; h[1]=(half_t)v0.y; h[2]=(half_t)v0.z; h[3]=(half_t)v0.w;
    h[4]=(half_t)v1.x; h[5]=(half_t)v1.y; h[6]=(half_t)v1.z; h[7]=(half_t)v1.w;
    *(half8*)(zdst + (size_t)row * 640 + c8) = h;
  } else if (b < 4224) {               // W1 [128][256] -> W1t [256][128]
    int i = (b - 4096) * 256 + tid;
    int n = i >> 7, k = i & 127;
    W1t[i] = (half_t)W1[k * 256 + n];
  } else if (b < 4608) {               // W2 [384][256] -> W2t [256][384]
    int i = (b - 4224) * 256 + tid;
    int n = i / 384, k = i - n * 384;
    W2t[i] = (half_t)W2[k * 256 + n];
  } else if (b < 5568) {               // Wout [640][366] -> Wot [384][640], zero-pad
    int i = (b - 4608) * 256 + tid;
    int n = i / 640, k = i - n * 640;
    Wot[i] = (half_t)((n < 366) ? Wout[k * 366 + n] : 0.f);
  } else {                             // identity table tails (z columns)
    if (tid < 128) {
      t2sc[256 + tid] = (half_t)1.f; t2sh[256 + tid] = (half_t)0.f;
      t2lo[256 + tid] = (half_t)(-65504.f);
    } else {
      int t = tid - 128;
      t3sc[512 + t] = (half_t)1.f; t3sh[512 + t] = (half_t)0.f;
      t3lo[512 + t] = (half_t)(-65504.f);
    }
  }
}

// ---------- GEMM: 128x128 tile, BK=32, 3-buffer ring pipeline, x32 MFMA ----------
// Schedule per tile: vmcnt(4) -> s_barrier -> stage(t+2) -> compute(t).
// 1 barrier per BK=32 (= R15's rate per K), counted vmcnt (no drain in loop),
// prefetch depth 2. LDS: 3 x 16KB buffers + BN tables (lgkm domain, so the
// counted vmcnt tracks ONLY stage loads). Chunk swizzle slot^(row&3).
template<bool STATS, bool TRANS, bool ALPHA>
__global__ __launch_bounds__(256) void k_gemm(
    const half_t* __restrict__ A, int lda, int K,
    const half_t* __restrict__ Bt,
    const float* __restrict__ bias,
    const half_t* __restrict__ tsc, const half_t* __restrict__ tsh,
    const half_t* __restrict__ tlo,
    half_t* __restrict__ o16, int ldo, int ncreal,
    float* __restrict__ ps, float* __restrict__ pq) {
  __shared__ __align__(16) char smem[53248];   // 3x16K buffers + 3x1280B tables
  const int tid  = threadIdx.x;
  const int lane = tid & 63;
  const int w    = tid >> 6;
  const int wr   = w >> 1, wc = w & 1;
  const int ml   = lane & 15, g = lane >> 4;
  const int brow = blockIdx.x * 128;
  const int bcol = blockIdx.y * 128;

  f32x4 acc[4][4];
#pragma unroll
  for (int i = 0; i < 4; i++)
#pragma unroll
    for (int j = 0; j < 4; j++) acc[i][j] = (f32x4){0.f, 0.f, 0.f, 0.f};

  const half_t* Abase = A  + (size_t)brow * lda;
  const half_t* Bbase = Bt + (size_t)bcol * K;
  const int nt = K >> 5;

  // stage tile t (BK=32: A 8KB = 512 chunks of 16B, B 8KB) into buffer p.
  // LDS dest is wave-uniform base (HW adds lane*16); global src pre-swizzled.
  auto stage = [&](int t, int p) {
    const int k0 = t * 32;
    char* dst = smem + p * 16384;
#pragma unroll
    for (int it = 0; it < 2; it++) {
      int cb = it * 256 + w * 64;            // wave-uniform chunk base
      int ch = cb + lane;                    // this lane's chunk
      int row = ch >> 2;
      int sc2 = (ch & 3) ^ (row & 3);        // pre-swizzled source octet
      __builtin_amdgcn_global_load_lds(
          (AS1 const void*)(Abase + (size_t)row * lda + k0 + sc2 * 8),
          (AS3 void*)(dst + cb * 16), 16, 0, 0);
      __builtin_amdgcn_global_load_lds(
          (AS1 const void*)(Bbase + (size_t)row * K + k0 + sc2 * 8),
          (AS3 void*)(dst + 8192 + cb * 16), 16, 0, 0);
    }
  };

  auto compute = [&](int t, int p) {
    const char* As = smem + p * 16384;
    const char* Bs = As + 8192;
    half8 sc, sh, lo;
    if (TRANS) {                             // LDS table read (broadcast, lgkm)
      const half_t* tb = (const half_t*)(smem + 49152);
      int o = (t * 4 + g) * 8;
      sc = *(const half8*)(tb + o);
      sh = *(const half8*)(tb + 640 + o);
      lo = *(const half8*)(tb + 1280 + o);
    }
    half8 af[4], bf[4];
#pragma unroll
    for (int fm = 0; fm < 4; fm++) {
      int row = wr * 64 + fm * 16 + ml;
      af[fm] = *(const half8*)(As + row * 64 + ((g ^ (row & 3)) << 4));
    }
    if (TRANS) {
#pragma unroll
      for (int fm = 0; fm < 4; fm++) af[fm] = bn8(af[fm], sc, sh, lo);
    }
#pragma unroll
    for (int fn = 0; fn < 4; fn++) {
      int row = wc * 64 + fn * 16 + ml;
      bf[fn] = *(const half8*)(Bs + row * 64 + ((g ^ (row & 3)) << 4));
    }
#pragma unroll
    for (int fm = 0; fm < 4; fm++)
#pragma unroll
      for (int fn = 0; fn < 4; fn++)
        acc[fm][fn] = __builtin_amdgcn_mfma_f32_16x16x32_f16(af[fm], bf[fn], acc[fm][fn], 0, 0, 0);
  };

  // prologue: tables -> LDS (lgkm), stage tiles 0,1; drain own ds_writes
  if (TRANS) {
    const int no = K >> 3;                    // octets per table
    for (int i = tid; i < 3 * no; i += 256) {
      int a = i / no, pos = i - a * no;
      const half_t* src = (a == 0 ? tsc : (a == 1 ? tsh : tlo)) + pos * 8;
      *(half8*)(smem + 49152 + a * 1280 + pos * 16) = *(const half8*)src;
    }
  }
  stage(0, 0);
  stage(1, 1);
  asm volatile("s_waitcnt lgkmcnt(0)" ::: "memory");

  for (int t = 0; t < nt - 1; t++) {
    asm volatile("s_waitcnt vmcnt(4)" ::: "memory");  // tile t landed; t+1 in flight
    __builtin_amdgcn_s_barrier();                     // t visible; compute(t-1) done by all
    if (t + 2 < nt) stage(t + 2, (t + 2) % 3);        // overwrites buf[(t-1)%3]: safe
    compute(t, t % 3);
  }
  asm volatile("s_waitcnt vmcnt(0)" ::: "memory");
  __builtin_amdgcn_s_barrier();
  compute(nt - 1, (nt - 1) % 3);
  __syncthreads();

#pragma unroll
  for (int fn = 0; fn < 4; fn++) {
    int col  = wc * 64 + fn * 16 + ml;
    int gcol = bcol + col;
    float bz = (gcol < ncreal) ? bias[gcol] : 0.f;
    float s = 0.f, q = 0.f;
    const bool al = ALPHA && (gcol < 90) && is_alpha(gcol);
#pragma unroll
    for (int fm = 0; fm < 4; fm++)
#pragma unroll
      for (int rr = 0; rr < 4; rr++) {
        float v = acc[fm][fn][rr] + bz;
        if (STATS) { s += v; q += v * v; }
        if (al) v = tanhf(v);
        acc[fm][fn][rr] = v;
      }
    if (STATS) {
      s += __shfl_xor(s, 16, 64); s += __shfl_xor(s, 32, 64);
      q += __shfl_xor(q, 16, 64); q += __shfl_xor(q, 32, 64);
      if (g == 0) {
        ps[(size_t)gcol * 1024 + blockIdx.x * 2 + wr] = s;
        pq[(size_t)gcol * 1024 + blockIdx.x * 2 + wr] = q;
      }
    }
  }

  // f16 output via LDS restage (coalesced half8)
  half_t* so = (half_t*)smem;  // [128][128] = 32KB
#pragma unroll
  for (int fn = 0; fn < 4; fn++)
#pragma unroll
    for (int fm = 0; fm < 4; fm++)
#pragma unroll
      for (int rr = 0; rr < 4; rr++)
        so[(wr * 64 + fm * 16 + g * 4 + rr) * 128 + wc * 64 + fn * 16 + ml] =
            (half_t)acc[fm][fn][rr];
  __syncthreads();
#pragma unroll
  for (int it = 0; it < 8; it++) {
    int r = it * 16 + (tid >> 4);
    int c = (tid & 15) * 8;
    *(half8*)(o16 + (size_t)(brow + r) * ldo + bcol + c) = *(const half8*)&so[r * 128 + c];
  }
}

// ---------- BN finalize -> f16 tables (one or two destinations) ----------
__global__ __launch_bounds__(256) void k_bnfinal(
    const float* __restrict__ ps, const float* __restrict__ pq,
    const float* __restrict__ gamma, const float* __restrict__ beta,
    half_t* __restrict__ scA, half_t* __restrict__ shA, half_t* __restrict__ loA,
    half_t* __restrict__ scB, half_t* __restrict__ shB, half_t* __restrict__ loB) {
  int c = blockIdx.x, t = threadIdx.x;
  float s = 0.f, q = 0.f;
#pragma unroll
  for (int i = 0; i < 4; i++) {
    s += ps[(size_t)c * 1024 + t + i * 256];
    q += pq[(size_t)c * 1024 + t + i * 256];
  }
#pragma unroll
  for (int o = 1; o < 64; o <<= 1) { s += __shfl_xor(s, o, 64); q += __shfl_xor(q, o, 64); }
  __shared__ float ss[4], qq[4];
  if ((t & 63) == 0) { ss[t >> 6] = s; qq[t >> 6] = q; }
  __syncthreads();
  if (t == 0) {
    s = ss[0] + ss[1] + ss[2] + ss[3];
    q = qq[0] + qq[1] + qq[2] + qq[3];
    float mu   = s * (1.f / NBATCH);
    float var  = fmaxf(q * (1.f / NBATCH) - mu * mu, 0.f);
    float rstd = rsqrtf(var + 1e-3f);
    float a  = gamma[c] * rstd;
    float sh = beta[c] - mu * a;
    scA[c] = (half_t)a; shA[c] = (half_t)sh; loA[c] = (half_t)0.f;
    if (scB) { scB[c] = (half_t)a; shB[c] = (half_t)sh; loB[c] = (half_t)0.f; }
  }
}

// ---------- softmax helpers (zb values already (l+g)/TAU) ----------
template<int L>
__device__ __forceinline__ void seg_norm(float* __restrict__ zr, int S, int Lr) {
  float v[L];
#pragma unroll
  for (int j = 0; j < L; j++) v[j] = (j < Lr) ? zr[S + j] : -1e30f;
  float m = -1e30f;
#pragma unroll
  for (int j = 0; j < L; j++) m = fmaxf(m, v[j]);
  float s = 0.f;
#pragma unroll
  for (int j = 0; j < L; j++) { float e = __expf(v[j] - m); v[j] = e; s += e; }
  const float inv = 1.0f / s;
#pragma unroll
  for (int j = 0; j < L; j++)
    if (j < Lr) zr[S + j] = v[j] * inv;
}

template<int H>
__device__ __forceinline__ void seg_quad(float* __restrict__ zr, int base, int n) {
  float v[H];
#pragma unroll
  for (int j = 0; j < H; j++) v[j] = (j < n) ? zr[base + j] : -1e30f;
  float m = -1e30f;
#pragma unroll
  for (int j = 0; j < H; j++) m = fmaxf(m, v[j]);
  m = fmaxf(m, __shfl_xor(m, 1, 64));
  m = fmaxf(m, __shfl_xor(m, 2, 64));
  float s = 0.f;
#pragma unroll
  for (int j = 0; j < H; j++) { float e = __expf(v[j] - m); v[j] = e; s += e; }
  s += __shfl_xor(s, 1, 64);
  s += __shfl_xor(s, 2, 64);
  const float inv = 1.0f / s;
#pragma unroll
  for (int j = 0; j < H; j++)
    if (j < n) zr[base + j] = v[j] * inv;
}

// ---------- gumbel-softmax: 16 rows/block, 256 thr, quad-lane bins ----------
__global__ __launch_bounds__(256, 6) void k_softmax(const half_t* __restrict__ lg,
                                                    const float* __restrict__ g,
                                                    float* __restrict__ out) {
  __shared__ float zb[16][373];  // 23.9 KB -> 6 blocks/CU
  const int tid  = threadIdx.x;
  const int row0 = blockIdx.x * 16;
  const size_t gbase = (size_t)row0 * 366;
  for (int i2 = tid; i2 < 16 * 183; i2 += 256) {
    int e0 = i2 * 2;
    int r = e0 / 366;
    int c = e0 - r * 366;
    const half_t* lp = lg + (size_t)(row0 + r) * 384 + c;
    float lx = (float)lp[0], ly = (float)lp[1];
    float2 gg = *(const float2*)(g + gbase + e0);
    zb[r][c]     = is_alpha(c)     ? lx : (lx + gg.x) * 5.0f;  // alpha already tanh'd
    zb[r][c + 1] = is_alpha(c + 1) ? ly : (ly + gg.y) * 5.0f;
  }
  __syncthreads();
  {
    const int lane = tid & 63;
    const int w    = tid >> 6;
    const int quad = lane & 3;
    float* zr = &zb[lane >> 2][0];
    switch (w) {
      case 0:
        seg_quad<25>(zr, 184 + quad * 25, 25);
        break;
      case 1:
        seg_quad<13>(zr, 120 + quad * 13 - (quad >> 1) * (quad & 1), 13 - (quad >> 1));
        seg_quad<8>(zr, 314 + quad * 8 - (quad >> 1) * (quad & 1), 8 - (quad >> 1));
        break;
      case 2: {
        int s0 = (quad == 0) ? 295 : (quad == 1) ? 107 : (quad == 2) ? 38 : 68;
        int l0 = (quad == 0) ? 12 : 10;
        int s1 = (quad == 0) ? 1 : (quad == 1) ? 21 : (quad == 2) ? 49 : 79;
        int s2 = (quad == 0) ? 0 : (quad == 1) ? 100 : (quad == 2) ? 174 : 290;
        int l2 = (quad == 0) ? 0 : 2;
        seg_norm<12>(zr, s0, l0);
        seg_norm<10>(zr, s1, 10);
        seg_norm<2>(zr, s2, l2);
        break;
      }
      default: {
        int s0 = (quad == 0) ? 90 : (quad == 1) ? 12 : (quad == 2) ? 60 : 102;
        int l0 = (quad == 0) ? 10 : (quad == 1) ? 8 : (quad == 2) ? 7 : 5;
        int s1 = (quad == 0) ? 348 : (quad == 1) ? 176 : (quad == 2) ? 359 : 307;
        int l1 = (quad == 0) ? 9 : (quad == 1) ? 8 : (quad == 2) ? 7 : 5;
        int s2 = (quad == 0) ? 312 : (quad == 1) ? 284 : (quad == 2) ? 32 : 170;
        int l2 = (quad == 0) ? 2 : (quad == 1) ? 6 : (quad == 2) ? 5 : 4;
        int s3 = (quad == 0) ? 117 : (quad == 1) ? 357 : (quad == 2) ? 292 : 344;
        int l3 = (quad == 0) ? 3 : (quad == 1) ? 2 : (quad == 2) ? 3 : 4;
        seg_norm<10>(zr, s0, l0);
        seg_norm<9>(zr, s1, l1);
        seg_norm<6>(zr, s2, l2);
        seg_norm<4>(zr, s3, l3);
        break;
      }
    }
  }
  __syncthreads();
  for (int i2 = tid; i2 < 16 * 183; i2 += 256) {
    int e0 = i2 * 2;
    int r = e0 / 366;
    int c = e0 - r * 366;
    float2 v;
    v.x = zb[r][c];
    v.y = zb[r][c + 1];
    *(float2*)(out + gbase + e0) = v;
  }
}

extern "C" void kernel_launch(void* const* d_in, const int* in_sizes, int n_in,
                              void* d_out, int out_size, void* d_ws, size_t ws_size,
                              hipStream_t stream) {
  const float* z      = (const float*)d_in[0];
  const float* g      = (const float*)d_in[1];
  const float* W1     = (const float*)d_in[2];
  const float* b1     = (const float*)d_in[3];
  const float* gamma1 = (const float*)d_in[4];
  const float* beta1  = (const float*)d_in[5];
  const float* W2     = (const float*)d_in[6];
  const float* b2     = (const float*)d_in[7];
  const float* gamma2 = (const float*)d_in[8];
  const float* beta2  = (const float*)d_in[9];
  const float* Wout   = (const float*)d_in[10];
  const float* bout   = (const float*)d_in[11];
  float* out = (float*)d_out;
  char* ws = (char*)d_ws;

  size_t off = 0;
  half_t* act = (half_t*)(ws + off); off += (size_t)NBATCH * 640 * 2;  // raw [h2|h1|z]
  half_t* lg  = (half_t*)(ws + off); off += (size_t)NBATCH * 384 * 2;  // f16 logits
  half_t* W1t = (half_t*)(ws + off); off += (size_t)256 * 128 * 2;
  half_t* W2t = (half_t*)(ws + off); off += (size_t)256 * 384 * 2;
  half_t* Wot = (half_t*)(ws + off); off += (size_t)384 * 640 * 2;
  float*  ps  = (float*)(ws + off);  off += (size_t)256 * 1024 * 4;
  float*  pq  = (float*)(ws + off);  off += (size_t)256 * 1024 * 4;
  half_t* t2sc = (half_t*)(ws + off); off += 1024;  // 384 used
  half_t* t2sh = (half_t*)(ws + off); off += 1024;
  half_t* t2lo = (half_t*)(ws + off); off += 1024;
  half_t* t3sc = (half_t*)(ws + off); off += 2048;  // 640 used
  half_t* t3sh = (half_t*)(ws + off); off += 2048;
  half_t* t3lo = (half_t*)(ws + off); off += 2048;
  (void)ws_size; (void)in_sizes; (void)n_in; (void)out_size;

  // merged prep (1 dispatch)
  k_prep<<<5569, 256, 0, stream>>>(z, act + 512, W1, W1t, W2, W2t, Wout, Wot,
                                   t2sc, t2sh, t2lo, t3sc, t3sh, t3lo);

  // layer 1: raw h1(f16, act cols 256..511) = z @ W1 + b1, fused stats
  k_gemm<true, false, false><<<dim3(512, 2), 256, 0, stream>>>(
      act + 512, 640, 128, W1t, b1, nullptr, nullptr, nullptr,
      act + 256, 640, 256, ps, pq);
  k_bnfinal<<<256, 256, 0, stream>>>(ps, pq, gamma1, beta1,
                                     t2sc, t2sh, t2lo, t3sc + 256, t3sh + 256, t3lo + 256);

  // layer 2: raw h2(f16, act cols 0..255) = bnrelu(h1)|z @ W2 + b2 (A-transformed)
  k_gemm<true, true, false><<<dim3(512, 2), 256, 0, stream>>>(
      act + 256, 640, 384, W2t, b2, t2sc, t2sh, t2lo,
      act + 0, 640, 256, ps, pq);
  k_bnfinal<<<256, 256, 0, stream>>>(ps, pq, gamma2, beta2,
                                     t3sc, t3sh, t3lo, nullptr, nullptr, nullptr);

  // output layer: f16 logits = bnrelu([h2|h1])|z @ Wout + bout (alpha cols tanh'd)
  k_gemm<false, true, true><<<dim3(512, 3), 256, 0, stream>>>(
      act, 640, 640, Wot, bout, t3sc, t3sh, t3lo,
      lg, 384, 366, nullptr, nullptr);

  // gumbel transform + segment normalize -> final f32 d_out
  k_softmax<<<NBATCH / 16, 256, 0, stream>>>(lg, g, out);
}

// Round 19
// 176.199 us; speedup vs baseline: 1.0107x; 1.0107x over previous
//
#include <hip/hip_runtime.h>

typedef _Float16 half_t;
typedef _Float16 half4 __attribute__((ext_vector_type(4)));
typedef _Float16 half8 __attribute__((ext_vector_type(8)));
typedef float f32x4 __attribute__((ext_vector_type(4)));

#define AS1 __attribute__((address_space(1)))
#define AS3 __attribute__((address_space(3)))

static constexpr int NBATCH = 65536;

__device__ __forceinline__ bool is_alpha(int c) {
  const unsigned long long AM0 =
      (1ull << 0) | (1ull << 11) | (1ull << 20) | (1ull << 31) | (1ull << 37) |
      (1ull << 48) | (1ull << 59);
  const unsigned long long AM1 = (1ull << 3) | (1ull << 14) | (1ull << 25);  // 67,78,89
  if (c >= 90) return false;
  return (((c < 64) ? (AM0 >> c) : (AM1 >> (c - 64))) & 1ull) != 0ull;
}

// BN+ReLU on a half8 fragment: packed fma + packed max (R14/R15 lesson).
__device__ __forceinline__ half8 bn8(half8 x, half8 sc, half8 sh, half8 lo) {
  return __builtin_elementwise_max(x * sc + sh, lo);
}

// ---------- merged prep: z cvt + 3 weight transposes + identity table tails ----------
__global__ __launch_bounds__(256) void k_prep(
    const float* __restrict__ z, half_t* __restrict__ zdst,
    const float* __restrict__ W1, half_t* __restrict__ W1t,
    const float* __restrict__ W2, half_t* __restrict__ W2t,
    const float* __restrict__ Wout, half_t* __restrict__ Wot,
    half_t* __restrict__ t2sc, half_t* __restrict__ t2sh, half_t* __restrict__ t2lo,
    half_t* __restrict__ t3sc, half_t* __restrict__ t3sh, half_t* __restrict__ t3lo) {
  const int b = blockIdx.x;
  const int tid = threadIdx.x;
  if (b < 4096) {
    size_t i = (size_t)b * 256 + tid;
    int row = (int)(i >> 4), c8 = (int)(i & 15) << 3;
    const float* s = z + (size_t)row * 128 + c8;
    float4 v0 = *(const float4*)s;
    float4 v1 = *(const float4*)(s + 4);
    half8 h;
    h[0]=(half_t)v0.x; h[1]=(half_t)v0.y; h[2]=(half_t)v0.z; h[3]=(half_t)v0.w;
    h[4]=(half_t)v1.x; h[5]=(half_t)v1.y; h[6]=(half_t)v1.z; h[7]=(half_t)v1.w;
    *(half8*)(zdst + (size_t)row * 640 + c8) = h;
  } else if (b < 4224) {               // W1 [128][256] -> W1t [256][128]
    int i = (b - 4096) * 256 + tid;
    int n = i >> 7, k = i & 127;
    W1t[i] = (half_t)W1[k * 256 + n];
  } else if (b < 4608) {               // W2 [384][256] -> W2t [256][384]
    int i = (b - 4224) * 256 + tid;
    int n = i / 384, k = i - n * 384;
    W2t[i] = (half_t)W2[k * 256 + n];
  } else if (b < 5568) {               // Wout [640][366] -> Wot [384][640], zero-pad
    int i = (b - 4608) * 256 + tid;
    int n = i / 640, k = i - n * 640;
    Wot[i] = (half_t)((n < 366) ? Wout[k * 366 + n] : 0.f);
  } else {                             // identity table tails (z columns)
    if (tid < 128) {
      t2sc[256 + tid] = (half_t)1.f; t2sh[256 + tid] = (half_t)0.f;
      t2lo[256 + tid] = (half_t)(-65504.f);
    } else {
      int t = tid - 128;
      t3sc[512 + t] = (half_t)1.f; t3sh[512 + t] = (half_t)0.f;
      t3lo[512 + t] = (half_t)(-65504.f);
    }
  }
}

// ---------- GEMM: 128x128 tile, BK=64, single-buffer (m97), x32 MFMA ----------
// Converged structure (R9/R16/R18 pipeline attempts all null): full-drain
// barrier per tile; cross-block wave overlap hides the drain at ~3-5 blocks/CU.
template<bool STATS, bool TRANS, bool ALPHA>
__global__ __launch_bounds__(256) void k_gemm(
    const half_t* __restrict__ A, int lda, int K,
    const half_t* __restrict__ Bt,
    const float* __restrict__ bias,
    const half_t* __restrict__ tsc, const half_t* __restrict__ tsh,
    const half_t* __restrict__ tlo,
    half_t* __restrict__ o16, int ldo, int ncreal,
    float* __restrict__ ps, float* __restrict__ pq) {
  __shared__ __align__(16) char smem[32768];   // A 16K + B 16K
  const int tid  = threadIdx.x;
  const int lane = tid & 63;
  const int w    = tid >> 6;
  const int wr   = w >> 1, wc = w & 1;
  const int ml   = lane & 15, g = lane >> 4;
  const int brow = blockIdx.x * 128;
  const int bcol = blockIdx.y * 128;
  const int sr  = lane >> 3;
  const int scg = (lane & 7) ^ sr;

  f32x4 acc[4][4];
#pragma unroll
  for (int i = 0; i < 4; i++)
#pragma unroll
    for (int j = 0; j < 4; j++) acc[i][j] = (f32x4){0.f, 0.f, 0.f, 0.f};

  const half_t* Abase = A  + (size_t)brow * lda;
  const half_t* Bbase = Bt + (size_t)bcol * K;
  const int nt = K >> 6;

  half_t* As = (half_t*)smem;
  half_t* Bs = (half_t*)(smem + 16384);

  for (int t = 0; t < nt; t++) {
    const int k0 = t * 64;
    // BN tables for this tile's two A k-octets (L2-hit; issued pre-barrier)
    half8 sc0, sh0, lo0, sc1, sh1, lo1;
    if (TRANS) {
      const int ka = k0 + g * 8, kb = k0 + 32 + g * 8;
      sc0 = *(const half8*)&tsc[ka]; sh0 = *(const half8*)&tsh[ka]; lo0 = *(const half8*)&tlo[ka];
      sc1 = *(const half8*)&tsc[kb]; sh1 = *(const half8*)&tsh[kb]; lo1 = *(const half8*)&tlo[kb];
    }
    if (t) __syncthreads();
#pragma unroll
    for (int it = 0; it < 4; it++) {
      int q = it * 4 + w;
      int r = q * 8 + sr;
      __builtin_amdgcn_global_load_lds(
          (AS1 const void*)(Abase + (size_t)r * lda + k0 + scg * 8),
          (AS3 void*)(As + q * 512), 16, 0, 0);
      __builtin_amdgcn_global_load_lds(
          (AS1 const void*)(Bbase + (size_t)r * K + k0 + scg * 8),
          (AS3 void*)(Bs + q * 512), 16, 0, 0);
    }
    __syncthreads();
#pragma unroll
    for (int t2 = 0; t2 < 2; t2++) {
      const int c4 = t2 * 4 + g;
      half8 af[4], bf[4];
#pragma unroll
      for (int fm = 0; fm < 4; fm++) {
        int row = wr * 64 + fm * 16 + ml;
        af[fm] = *(const half8*)((const char*)As + row * 128 + ((c4 ^ (row & 7)) << 4));
      }
      if (TRANS) {
        const half8 sc = t2 ? sc1 : sc0;
        const half8 sh = t2 ? sh1 : sh0;
        const half8 lo = t2 ? lo1 : lo0;
#pragma unroll
        for (int fm = 0; fm < 4; fm++) af[fm] = bn8(af[fm], sc, sh, lo);
      }
#pragma unroll
      for (int fn = 0; fn < 4; fn++) {
        int row = wc * 64 + fn * 16 + ml;
        bf[fn] = *(const half8*)((const char*)Bs + row * 128 + ((c4 ^ (row & 7)) << 4));
      }
#pragma unroll
      for (int fm = 0; fm < 4; fm++)
#pragma unroll
        for (int fn = 0; fn < 4; fn++)
          acc[fm][fn] = __builtin_amdgcn_mfma_f32_16x16x32_f16(af[fm], bf[fn], acc[fm][fn], 0, 0, 0);
    }
  }
  __syncthreads();

#pragma unroll
  for (int fn = 0; fn < 4; fn++) {
    int col  = wc * 64 + fn * 16 + ml;
    int gcol = bcol + col;
    float bz = (gcol < ncreal) ? bias[gcol] : 0.f;
    float s = 0.f, q = 0.f;
    const bool al = ALPHA && (gcol < 90) && is_alpha(gcol);
#pragma unroll
    for (int fm = 0; fm < 4; fm++)
#pragma unroll
      for (int rr = 0; rr < 4; rr++) {
        float v = acc[fm][fn][rr] + bz;
        if (STATS) { s += v; q += v * v; }
        if (al) v = tanhf(v);
        acc[fm][fn][rr] = v;
      }
    if (STATS) {
      s += __shfl_xor(s, 16, 64); s += __shfl_xor(s, 32, 64);
      q += __shfl_xor(q, 16, 64); q += __shfl_xor(q, 32, 64);
      if (g == 0) {
        ps[(size_t)gcol * 1024 + blockIdx.x * 2 + wr] = s;
        pq[(size_t)gcol * 1024 + blockIdx.x * 2 + wr] = q;
      }
    }
  }

  // f16 output via LDS restage (coalesced half8)
  half_t* so = (half_t*)smem;  // [128][128]
#pragma unroll
  for (int fn = 0; fn < 4; fn++)
#pragma unroll
    for (int fm = 0; fm < 4; fm++)
#pragma unroll
      for (int rr = 0; rr < 4; rr++)
        so[(wr * 64 + fm * 16 + g * 4 + rr) * 128 + wc * 64 + fn * 16 + ml] =
            (half_t)acc[fm][fn][rr];
  __syncthreads();
#pragma unroll
  for (int it = 0; it < 8; it++) {
    int r = it * 16 + (tid >> 4);
    int c = (tid & 15) * 8;
    *(half8*)(o16 + (size_t)(brow + r) * ldo + bcol + c) = *(const half8*)&so[r * 128 + c];
  }
}

// ---------- BN finalize -> f16 tables (one or two destinations) ----------
__global__ __launch_bounds__(256) void k_bnfinal(
    const float* __restrict__ ps, const float* __restrict__ pq,
    const float* __restrict__ gamma, const float* __restrict__ beta,
    half_t* __restrict__ scA, half_t* __restrict__ shA, half_t* __restrict__ loA,
    half_t* __restrict__ scB, half_t* __restrict__ shB, half_t* __restrict__ loB) {
  int c = blockIdx.x, t = threadIdx.x;
  float s = 0.f, q = 0.f;
#pragma unroll
  for (int i = 0; i < 4; i++) {
    s += ps[(size_t)c * 1024 + t + i * 256];
    q += pq[(size_t)c * 1024 + t + i * 256];
  }
#pragma unroll
  for (int o = 1; o < 64; o <<= 1) { s += __shfl_xor(s, o, 64); q += __shfl_xor(q, o, 64); }
  __shared__ float ss[4], qq[4];
  if ((t & 63) == 0) { ss[t >> 6] = s; qq[t >> 6] = q; }
  __syncthreads();
  if (t == 0) {
    s = ss[0] + ss[1] + ss[2] + ss[3];
    q = qq[0] + qq[1] + qq[2] + qq[3];
    float mu   = s * (1.f / NBATCH);
    float var  = fmaxf(q * (1.f / NBATCH) - mu * mu, 0.f);
    float rstd = rsqrtf(var + 1e-3f);
    float a  = gamma[c] * rstd;
    float sh = beta[c] - mu * a;
    scA[c] = (half_t)a; shA[c] = (half_t)sh; loA[c] = (half_t)0.f;
    if (scB) { scB[c] = (half_t)a; shB[c] = (half_t)sh; loB[c] = (half_t)0.f; }
  }
}

// ---------- softmax helpers (zb values already (l+g)/TAU) ----------
template<int L>
__device__ __forceinline__ void seg_norm(float* __restrict__ zr, int S, int Lr) {
  float v[L];
#pragma unroll
  for (int j = 0; j < L; j++) v[j] = (j < Lr) ? zr[S + j] : -1e30f;
  float m = -1e30f;
#pragma unroll
  for (int j = 0; j < L; j++) m = fmaxf(m, v[j]);
  float s = 0.f;
#pragma unroll
  for (int j = 0; j < L; j++) { float e = __expf(v[j] - m); v[j] = e; s += e; }
  const float inv = 1.0f / s;
#pragma unroll
  for (int j = 0; j < L; j++)
    if (j < Lr) zr[S + j] = v[j] * inv;
}

template<int H>
__device__ __forceinline__ void seg_quad(float* __restrict__ zr, int base, int n) {
  float v[H];
#pragma unroll
  for (int j = 0; j < H; j++) v[j] = (j < n) ? zr[base + j] : -1e30f;
  float m = -1e30f;
#pragma unroll
  for (int j = 0; j < H; j++) m = fmaxf(m, v[j]);
  m = fmaxf(m, __shfl_xor(m, 1, 64));
  m = fmaxf(m, __shfl_xor(m, 2, 64));
  float s = 0.f;
#pragma unroll
  for (int j = 0; j < H; j++) { float e = __expf(v[j] - m); v[j] = e; s += e; }
  s += __shfl_xor(s, 1, 64);
  s += __shfl_xor(s, 2, 64);
  const float inv = 1.0f / s;
#pragma unroll
  for (int j = 0; j < H; j++)
    if (j < n) zr[base + j] = v[j] * inv;
}

// ---------- gumbel-softmax: 16 rows/block, 256 thr, quad-lane bins ----------
__global__ __launch_bounds__(256, 6) void k_softmax(const half_t* __restrict__ lg,
                                                    const float* __restrict__ g,
                                                    float* __restrict__ out) {
  __shared__ float zb[16][373];  // 23.9 KB -> 6 blocks/CU
  const int tid  = threadIdx.x;
  const int row0 = blockIdx.x * 16;
  const size_t gbase = (size_t)row0 * 366;
  for (int i2 = tid; i2 < 16 * 183; i2 += 256) {
    int e0 = i2 * 2;
    int r = e0 / 366;
    int c = e0 - r * 366;
    const half_t* lp = lg + (size_t)(row0 + r) * 384 + c;
    float lx = (float)lp[0], ly = (float)lp[1];
    float2 gg = *(const float2*)(g + gbase + e0);
    zb[r][c]     = is_alpha(c)     ? lx : (lx + gg.x) * 5.0f;  // alpha already tanh'd
    zb[r][c + 1] = is_alpha(c + 1) ? ly : (ly + gg.y) * 5.0f;
  }
  __syncthreads();
  {
    const int lane = tid & 63;
    const int w    = tid >> 6;
    const int quad = lane & 3;
    float* zr = &zb[lane >> 2][0];
    switch (w) {
      case 0:
        seg_quad<25>(zr, 184 + quad * 25, 25);
        break;
      case 1:
        seg_quad<13>(zr, 120 + quad * 13 - (quad >> 1) * (quad & 1), 13 - (quad >> 1));
        seg_quad<8>(zr, 314 + quad * 8 - (quad >> 1) * (quad & 1), 8 - (quad >> 1));
        break;
      case 2: {
        int s0 = (quad == 0) ? 295 : (quad == 1) ? 107 : (quad == 2) ? 38 : 68;
        int l0 = (quad == 0) ? 12 : 10;
        int s1 = (quad == 0) ? 1 : (quad == 1) ? 21 : (quad == 2) ? 49 : 79;
        int s2 = (quad == 0) ? 0 : (quad == 1) ? 100 : (quad == 2) ? 174 : 290;
        int l2 = (quad == 0) ? 0 : 2;
        seg_norm<12>(zr, s0, l0);
        seg_norm<10>(zr, s1, 10);
        seg_norm<2>(zr, s2, l2);
        break;
      }
      default: {
        int s0 = (quad == 0) ? 90 : (quad == 1) ? 12 : (quad == 2) ? 60 : 102;
        int l0 = (quad == 0) ? 10 : (quad == 1) ? 8 : (quad == 2) ? 7 : 5;
        int s1 = (quad == 0) ? 348 : (quad == 1) ? 176 : (quad == 2) ? 359 : 307;
        int l1 = (quad == 0) ? 9 : (quad == 1) ? 8 : (quad == 2) ? 7 : 5;
        int s2 = (quad == 0) ? 312 : (quad == 1) ? 284 : (quad == 2) ? 32 : 170;
        int l2 = (quad == 0) ? 2 : (quad == 1) ? 6 : (quad == 2) ? 5 : 4;
        int s3 = (quad == 0) ? 117 : (quad == 1) ? 357 : (quad == 2) ? 292 : 344;
        int l3 = (quad == 0) ? 3 : (quad == 1) ? 2 : (quad == 2) ? 3 : 4;
        seg_norm<10>(zr, s0, l0);
        seg_norm<9>(zr, s1, l1);
        seg_norm<6>(zr, s2, l2);
        seg_norm<4>(zr, s3, l3);
        break;
      }
    }
  }
  __syncthreads();
  for (int i2 = tid; i2 < 16 * 183; i2 += 256) {
    int e0 = i2 * 2;
    int r = e0 / 366;
    int c = e0 - r * 366;
    float2 v;
    v.x = zb[r][c];
    v.y = zb[r][c + 1];
    *(float2*)(out + gbase + e0) = v;
  }
}

extern "C" void kernel_launch(void* const* d_in, const int* in_sizes, int n_in,
                              void* d_out, int out_size, void* d_ws, size_t ws_size,
                              hipStream_t stream) {
  const float* z      = (const float*)d_in[0];
  const float* g      = (const float*)d_in[1];
  const float* W1     = (const float*)d_in[2];
  const float* b1     = (const float*)d_in[3];
  const float* gamma1 = (const float*)d_in[4];
  const float* beta1  = (const float*)d_in[5];
  const float* W2     = (const float*)d_in[6];
  const float* b2     = (const float*)d_in[7];
  const float* gamma2 = (const float*)d_in[8];
  const float* beta2  = (const float*)d_in[9];
  const float* Wout   = (const float*)d_in[10];
  const float* bout   = (const float*)d_in[11];
  float* out = (float*)d_out;
  char* ws = (char*)d_ws;

  size_t off = 0;
  half_t* act = (half_t*)(ws + off); off += (size_t)NBATCH * 640 * 2;  // raw [h2|h1|z]
  half_t* lg  = (half_t*)(ws + off); off += (size_t)NBATCH * 384 * 2;  // f16 logits
  half_t* W1t = (half_t*)(ws + off); off += (size_t)256 * 128 * 2;
  half_t* W2t = (half_t*)(ws + off); off += (size_t)256 * 384 * 2;
  half_t* Wot = (half_t*)(ws + off); off += (size_t)384 * 640 * 2;
  float*  ps  = (float*)(ws + off);  off += (size_t)256 * 1024 * 4;
  float*  pq  = (float*)(ws + off);  off += (size_t)256 * 1024 * 4;
  half_t* t2sc = (half_t*)(ws + off); off += 1024;  // 384 used
  half_t* t2sh = (half_t*)(ws + off); off += 1024;
  half_t* t2lo = (half_t*)(ws + off); off += 1024;
  half_t* t3sc = (half_t*)(ws + off); off += 2048;  // 640 used
  half_t* t3sh = (half_t*)(ws + off); off += 2048;
  half_t* t3lo = (half_t*)(ws + off); off += 2048;
  (void)ws_size; (void)in_sizes; (void)n_in; (void)out_size;

  // merged prep (1 dispatch)
  k_prep<<<5569, 256, 0, stream>>>(z, act + 512, W1, W1t, W2, W2t, Wout, Wot,
                                   t2sc, t2sh, t2lo, t3sc, t3sh, t3lo);

  // layer 1: raw h1(f16, act cols 256..511) = z @ W1 + b1, fused stats
  k_gemm<true, false, false><<<dim3(512, 2), 256, 0, stream>>>(
      act + 512, 640, 128, W1t, b1, nullptr, nullptr, nullptr,
      act + 256, 640, 256, ps, pq);
  k_bnfinal<<<256, 256, 0, stream>>>(ps, pq, gamma1, beta1,
                                     t2sc, t2sh, t2lo, t3sc + 256, t3sh + 256, t3lo + 256);

  // layer 2: raw h2(f16, act cols 0..255) = bnrelu(h1)|z @ W2 + b2 (A-transformed)
  k_gemm<true, true, false><<<dim3(512, 2), 256, 0, stream>>>(
      act + 256, 640, 384, W2t, b2, t2sc, t2sh, t2lo,
      act + 0, 640, 256, ps, pq);
  k_bnfinal<<<256, 256, 0, stream>>>(ps, pq, gamma2, beta2,
                                     t3sc, t3sh, t3lo, nullptr, nullptr, nullptr);

  // output layer: f16 logits = bnrelu([h2|h1])|z @ Wout + bout (alpha cols tanh'd)
  k_gemm<false, true, true><<<dim3(512, 3), 256, 0, stream>>>(
      act, 640, 640, Wot, bout, t3sc, t3sh, t3lo,
      lg, 384, 366, nullptr, nullptr);

  // gumbel transform + segment normalize -> final f32 d_out
  k_softmax<<<NBATCH / 16, 256, 0, stream>>>(lg, g, out);
}